// Round 1
// baseline (781.282 us; speedup 1.0000x reference)
//
#include <hip/hip_runtime.h>

// Problem constants
#define TOTAL_DIM 24976   // 400 + 60*256 + 36*256
#define N_ROWS    97      // 1 + 60 + 36
#define D_MODEL   512
#define EPSLN     1e-5f

// grid decomposition: 32 output rows per workgroup (main path)
#define NB0 64
#define NB1 3840
#define NB2 2304

// Wt (bf16, transposed, k-padded) layout in d_ws:
//  split0: [512][416] at elem 0        (212992 elems)
//  split1: [512][256] at elem 212992   (131072 elems)
//  split2: [512][256] at elem 344064   (131072 elems)
#define WT_TOTAL 475136
#define WT_BYTES (WT_TOTAL * 2)

typedef __attribute__((ext_vector_type(8))) short frag8;   // 8 bf16 = 4 VGPRs
typedef __attribute__((ext_vector_type(4))) float frag4;   // 4 fp32 acc

__device__ __forceinline__ unsigned short f2b(float f) {
  // fp32 -> bf16 round-to-nearest-even
  unsigned u = __float_as_uint(f);
  u = u + 0x7fffu + ((u >> 16) & 1u);
  return (unsigned short)(u >> 16);
}

__device__ __forceinline__ unsigned cvt2bf(float lo, float hi) {
  // packs 2 fp32 -> 2 bf16 (RNE), single instruction; same rounding as f2b
  unsigned r;
  asm("v_cvt_pk_bf16_f32 %0, %1, %2" : "=v"(r) : "v"(lo), "v"(hi));
  return r;
}

// ---------------- prep: W fp32 [l][512] -> bf16 W^T [512][KP] (zero pad k>=l) ----
// LDS 32x33 tile transpose: both global read (over n) and write (over kp) coalesced.
// grid: 208 tiles (S0: 13 kp-tiles x 16 n-tiles) + 128 (S1: 8x16) + 128 (S2: 8x16)
__global__ void __launch_bounds__(256) prep_wt(const float* __restrict__ W0,
                                               const float* __restrict__ W1,
                                               const float* __restrict__ W2,
                                               unsigned short* __restrict__ wt) {
  __shared__ float tile[32][33];
  int bid = blockIdx.x;
  const float* W;
  int L, KP, WTO, kt, ntile;
  if (bid < 208) {
    W = W0; L = 400; KP = 416; WTO = 0;
    kt = bid % 13; ntile = bid / 13;
  } else if (bid < 336) {
    W = W1; L = 256; KP = 256; WTO = 212992;
    int b = bid - 208; kt = b & 7; ntile = b >> 3;
  } else {
    W = W2; L = 256; KP = 256; WTO = 344064;
    int b = bid - 336; kt = b & 7; ntile = b >> 3;
  }
  const int tx = threadIdx.x & 31, ty = threadIdx.x >> 5;
#pragma unroll
  for (int i = 0; i < 4; ++i) {
    int k = kt * 32 + ty + i * 8;
    int n = ntile * 32 + tx;
    tile[ty + i * 8][tx] = (k < L) ? W[k * 512 + n] : 0.f;   // coalesced over n
  }
  __syncthreads();
#pragma unroll
  for (int i = 0; i < 4; ++i) {
    int n  = ntile * 32 + ty + i * 8;
    int kp = kt * 32 + tx;
    wt[WTO + n * KP + kp] = f2b(tile[tx][ty + i * 8]);       // coalesced over kp
  }
}

// ---------------- fused GEMM + bias + ReLU + LayerNorm (MFMA, no-LDS GEMM) -------
// one workgroup = 32 rows x 512 cols (full N -> LN is workgroup-local)
// wave w covers cols [w*128, w*128+128) as 8 n-tiles; 2 m-tiles of 16 rows.
// B slices have ZERO cross-wave reuse and wt (0.95 MB) is L2-resident ->
// load B fragments straight from global (16B/lane). A (shared x4 waves) comes
// from L1 after the first wave touches it. No barriers in the K loop at all;
// LDS only holds the 1.25 KB LayerNorm cross-wave reduction.
template <int S>
__device__ __forceinline__ void run_split(
    int blk,
    const float* __restrict__ x, const unsigned short* __restrict__ wt,
    const float* __restrict__ bias, const float* __restrict__ gam,
    const float* __restrict__ bet, float* __restrict__ out) {
  constexpr int L     = (S == 0) ? 400 : 256;       // true K
  constexpr int KP    = (S == 0) ? 416 : 256;       // padded K (mult of 32)
  constexpr int START = (S == 0) ? 0 : (S == 1) ? 400 : 15760;
  constexpr int KK    = (S == 0) ? 1 : (S == 1) ? 60 : 36;   // slices
  constexpr int OFF   = (S == 0) ? 0 : (S == 1) ? 1 : 61;    // row offset in output
  constexpr int WTO   = (S == 0) ? 0 : (S == 1) ? 212992 : 344064;
  constexpr int NSTEP = KP / 32;

  __shared__ float red[4][32][2];
  __shared__ float stat[32][2];

  const int tid  = threadIdx.x;
  const int lane = tid & 63, wave = tid >> 6;
  const int q = lane >> 4, c = lane & 15;
  const int m_base = blk * 32;

  // A fragment source: row = m_base + mt*16 + c, k = t*32 + q*8 .. +8 (fp32)
  const float* ap[2];
#pragma unroll
  for (int mt = 0; mt < 2; ++mt) {
    int m = m_base + mt * 16 + c;
    int bb = m / KK, jj = m - bb * KK;        // const divisor -> magic mul
    ap[mt] = x + (size_t)bb * TOTAL_DIM + START + jj * L + q * 8;
  }
  // B fragment source: n-row = wave*128 + nt*16 + c, k = t*32 + q*8 .. +8 (bf16)
  const unsigned short* bp[8];
#pragma unroll
  for (int nt = 0; nt < 8; ++nt) {
    int n = wave * 128 + nt * 16 + c;
    bp[nt] = wt + WTO + n * KP + q * 8;
  }

  frag4 acc[2][8];
#pragma unroll
  for (int mt = 0; mt < 2; ++mt)
#pragma unroll
    for (int nt = 0; nt < 8; ++nt) {
      frag4 z = {0.f, 0.f, 0.f, 0.f};
      acc[mt][nt] = z;
    }

  // ---- K loop: no LDS, no barriers. Imm offsets fold into the loads.
  for (int t = 0; t < NSTEP; ++t) {
    frag8 bf[8];
#pragma unroll
    for (int nt = 0; nt < 8; ++nt)
      bf[nt] = *(const frag8*)(bp[nt] + t * 32);

    frag8 af[2];
#pragma unroll
    for (int mt = 0; mt < 2; ++mt) {
      union { frag8 f; unsigned u[4]; } ua;
      if (S == 0 && (t * 32 + q * 8) >= L) {
        // K=400: k-chunks are 8-aligned and 400%8==0 -> whole frag valid or zero
        ua.u[0] = 0u; ua.u[1] = 0u; ua.u[2] = 0u; ua.u[3] = 0u;
      } else {
        float4 lo = *(const float4*)(ap[mt] + t * 32);
        float4 hi = *(const float4*)(ap[mt] + t * 32 + 4);
        ua.u[0] = cvt2bf(lo.x, lo.y);
        ua.u[1] = cvt2bf(lo.z, lo.w);
        ua.u[2] = cvt2bf(hi.x, hi.y);
        ua.u[3] = cvt2bf(hi.z, hi.w);
      }
      af[mt] = ua.f;
    }

#pragma unroll
    for (int nt = 0; nt < 8; ++nt) {
      acc[0][nt] = __builtin_amdgcn_mfma_f32_16x16x32_bf16(af[0], bf[nt], acc[0][nt], 0, 0, 0);
      acc[1][nt] = __builtin_amdgcn_mfma_f32_16x16x32_bf16(af[1], bf[nt], acc[1][nt], 0, 0, 0);
    }
  }

  // ---- epilogue: bias + ReLU + LayerNorm, all from registers
  const int colbase = wave * 128 + c;
  float bv[8], gv[8], ev[8];
#pragma unroll
  for (int nt = 0; nt < 8; ++nt) {
    int col = colbase + nt * 16;
    bv[nt] = bias[col];
    gv[nt] = gam[col];
    ev[nt] = bet[col];
  }

  // C/D layout: col = lane&15 (c), row = q*4 + reg  [m89-verified]
#pragma unroll
  for (int mt = 0; mt < 2; ++mt) {
    float s[4] = {0.f, 0.f, 0.f, 0.f}, s2[4] = {0.f, 0.f, 0.f, 0.f};
#pragma unroll
    for (int nt = 0; nt < 8; ++nt)
#pragma unroll
      for (int r = 0; r < 4; ++r) {
        float h = acc[mt][nt][r] + bv[nt];
        h = fmaxf(h, 0.f);
        acc[mt][nt][r] = h;
        s[r] += h;
        s2[r] += h * h;
      }
#pragma unroll
    for (int r = 0; r < 4; ++r) {
      float a = s[r], b2 = s2[r];
#pragma unroll
      for (int msk = 1; msk < 16; msk <<= 1) {  // reduce across 16 cols (same q)
        a += __shfl_xor(a, msk, 64);
        b2 += __shfl_xor(b2, msk, 64);
      }
      if (c == 0) {
        int row = mt * 16 + q * 4 + r;
        red[wave][row][0] = a;
        red[wave][row][1] = b2;
      }
    }
  }
  __syncthreads();
  if (tid < 32) {
    float s = 0.f, s2 = 0.f;
#pragma unroll
    for (int w = 0; w < 4; ++w) {
      s  += red[w][tid][0];
      s2 += red[w][tid][1];
    }
    float mu  = s * (1.f / 512.f);
    float var = s2 * (1.f / 512.f) - mu * mu;
    stat[tid][0] = mu;
    stat[tid][1] = rsqrtf(var + EPSLN);
  }
  __syncthreads();

#pragma unroll
  for (int mt = 0; mt < 2; ++mt)
#pragma unroll
    for (int r = 0; r < 4; ++r) {
      int row = mt * 16 + q * 4 + r;
      float mu = stat[row][0], sc = stat[row][1];
      int m = m_base + row;
      int bb = m / KK, jj = m - bb * KK;   // const divisor -> magic mul
      size_t orow = (size_t)bb * N_ROWS + OFF + jj;
      float* op = out + orow * D_MODEL + colbase;
#pragma unroll
      for (int nt = 0; nt < 8; ++nt)
        op[nt * 16] = (acc[mt][nt][r] - mu) * sc * gv[nt] + ev[nt];
    }
}

__global__ void __launch_bounds__(256, 3) fused_kernel(
    const float* __restrict__ x, const unsigned short* __restrict__ wt,
    const float* __restrict__ b0, const float* __restrict__ g0, const float* __restrict__ e0,
    const float* __restrict__ b1, const float* __restrict__ g1, const float* __restrict__ e1,
    const float* __restrict__ b2, const float* __restrict__ g2, const float* __restrict__ e2,
    float* __restrict__ out) {
  int bid = blockIdx.x;
  if (bid < NB0)
    run_split<0>(bid, x, wt, b0, g0, e0, out);
  else if (bid < NB0 + NB1)
    run_split<1>(bid - NB0, x, wt, b1, g1, e1, out);
  else
    run_split<2>(bid - NB0 - NB1, x, wt, b2, g2, e2, out);
}

// ---------------- fallback: fp32 vector path, zero workspace ---------------------
// one block = one output row. Correct-but-slow; only used if ws_size is too small.
template <int S>
__global__ void __launch_bounds__(256) fallback_split(
    const float* __restrict__ x, const float* __restrict__ W,
    const float* __restrict__ bias, const float* __restrict__ gam,
    const float* __restrict__ bet, float* __restrict__ out) {
  constexpr int L     = (S == 0) ? 400 : 256;
  constexpr int START = (S == 0) ? 0 : (S == 1) ? 400 : 15760;
  constexpr int KK    = (S == 0) ? 1 : (S == 1) ? 60 : 36;
  constexpr int OFF   = (S == 0) ? 0 : (S == 1) ? 1 : 61;

  __shared__ float xs[400];
  __shared__ float rs[4], rs2[4];

  int m = blockIdx.x;
  int bb = m / KK, jj = m - bb * KK;
  const float* xp = x + (size_t)bb * TOTAL_DIM + START + jj * L;
  for (int k = threadIdx.x; k < L; k += 256) xs[k] = xp[k];
  __syncthreads();

  float h[2];
#pragma unroll
  for (int i = 0; i < 2; ++i) {
    int col = threadIdx.x + i * 256;
    float acc = 0.f;
    for (int k = 0; k < L; ++k) acc += xs[k] * W[k * 512 + col];
    h[i] = fmaxf(acc + bias[col], 0.f);
  }

  float s = h[0] + h[1], s2 = h[0] * h[0] + h[1] * h[1];
#pragma unroll
  for (int msk = 1; msk < 64; msk <<= 1) {
    s  += __shfl_xor(s, msk, 64);
    s2 += __shfl_xor(s2, msk, 64);
  }
  int wave = threadIdx.x >> 6, lane = threadIdx.x & 63;
  if (lane == 0) { rs[wave] = s; rs2[wave] = s2; }
  __syncthreads();
  s  = rs[0] + rs[1] + rs[2] + rs[3];
  s2 = rs2[0] + rs2[1] + rs2[2] + rs2[3];
  float mu  = s * (1.f / 512.f);
  float var = s2 * (1.f / 512.f) - mu * mu;
  float sc  = rsqrtf(var + EPSLN);

  float* op = out + ((size_t)bb * N_ROWS + OFF + jj) * D_MODEL;
#pragma unroll
  for (int i = 0; i < 2; ++i) {
    int col = threadIdx.x + i * 256;
    op[col] = (h[i] - mu) * sc * gam[col] + bet[col];
  }
}

extern "C" void kernel_launch(void* const* d_in, const int* in_sizes, int n_in,
                              void* d_out, int out_size, void* d_ws, size_t ws_size,
                              hipStream_t stream) {
  const float* x  = (const float*)d_in[0];
  const float* W0 = (const float*)d_in[1];
  const float* b0 = (const float*)d_in[2];
  const float* g0 = (const float*)d_in[3];
  const float* e0 = (const float*)d_in[4];
  const float* W1 = (const float*)d_in[5];
  const float* b1 = (const float*)d_in[6];
  const float* g1 = (const float*)d_in[7];
  const float* e1 = (const float*)d_in[8];
  const float* W2 = (const float*)d_in[9];
  const float* b2 = (const float*)d_in[10];
  const float* g2 = (const float*)d_in[11];
  const float* e2 = (const float*)d_in[12];
  float* out = (float*)d_out;

  if (ws_size >= (size_t)WT_BYTES) {
    // fast path: bf16 MFMA, fused GEMM+bias+ReLU+LN, no-LDS GEMM K loop
    unsigned short* wt = (unsigned short*)d_ws;
    prep_wt<<<464, 256, 0, stream>>>(W0, W1, W2, wt);
    fused_kernel<<<NB0 + NB1 + NB2, 256, 0, stream>>>(
        x, wt, b0, g0, e0, b1, g1, e1, b2, g2, e2, out);
  } else {
    // zero-workspace fp32 fallback (correct, slower)
    fallback_split<0><<<2048,   256, 0, stream>>>(x, W0, b0, g0, e0, out);
    fallback_split<1><<<122880, 256, 0, stream>>>(x, W1, b1, g1, e1, out);
    fallback_split<2><<<73728,  256, 0, stream>>>(x, W2, b2, g2, e2, out);
  }
}

// Round 3
// 681.012 us; speedup vs baseline: 1.1472x; 1.1472x over previous
//
#include <hip/hip_runtime.h>

// Problem constants
#define TOTAL_DIM 24976   // 400 + 60*256 + 36*256
#define N_ROWS    97      // 1 + 60 + 36
#define D_MODEL   512
#define EPSLN     1e-5f

// grid decomposition: 64 output rows per workgroup (main path)
#define NB0 32     // 2048/64
#define NB1 1920   // 122880/64
#define NB2 1152   // 73728/64

// Wt (bf16, MFMA-FRAGMENT-order, k-padded) layout in d_ws (elem = bf16):
//  per split: frag f = nt*NSTEP + t holds 512 elems: [lane 0..63][j 0..7]
//   value = W^T[n = nt*16 + (lane&15)][k = t*32 + (lane>>4)*8 + j]
//  split0: NSTEP=13 (KP=416), base elem 0        (32*13*512 = 212992)
//  split1: NSTEP=8  (KP=256), base elem 212992   (32*8*512  = 131072)
//  split2: NSTEP=8  (KP=256), base elem 344064   (131072)
#define WT_TOTAL 475136
#define WT_BYTES (WT_TOTAL * 2)

// dynamic LDS for fused kernel: A slab 64*832 (split0 worst) + red 8192 + stat 512
#define SMEM_FUSED 61952

typedef __attribute__((ext_vector_type(8))) short frag8;   // 8 bf16 = 4 VGPRs
typedef __attribute__((ext_vector_type(4))) float frag4;   // 4 fp32 acc

__device__ __forceinline__ unsigned short f2b(float f) {
  // fp32 -> bf16 round-to-nearest-even
  unsigned u = __float_as_uint(f);
  u = u + 0x7fffu + ((u >> 16) & 1u);
  return (unsigned short)(u >> 16);
}

__device__ __forceinline__ unsigned cvt2bf(float lo, float hi) {
  // packs 2 fp32 -> 2 bf16 (RNE), single instruction; same rounding as f2b
  unsigned r;
  asm("v_cvt_pk_bf16_f32 %0, %1, %2" : "=v"(r) : "v"(lo), "v"(hi));
  return r;
}

// ---------------- prep: W fp32 [l][512] -> bf16 W^T in MFMA-fragment order ------
// one thread per uint2 (4 bf16). 464 blocks * 256 = 118784 = WT_TOTAL/4 threads.
__global__ void __launch_bounds__(256) prep_wt(const float* __restrict__ W0,
                                               const float* __restrict__ W1,
                                               const float* __restrict__ W2,
                                               unsigned short* __restrict__ wt) {
  int i = blockIdx.x * 256 + threadIdx.x;   // uint2 index, 0..118783
  if (i >= WT_TOTAL / 4) return;
  const float* W; int L, NSTEP, u;
  if (i < 53248)      { W = W0; L = 400; NSTEP = 13; u = i; }
  else if (i < 86016) { W = W1; L = 256; NSTEP = 8;  u = i - 53248; }
  else                { W = W2; L = 256; NSTEP = 8;  u = i - 86016; }
  int j4 = u & 1;                 // which 4-element half of the lane's 8
  int l  = (u >> 1) & 63;         // lane
  int fi = u >> 7;                // frag index = nt*NSTEP + t
  int t  = fi % NSTEP;
  int nt = fi / NSTEP;
  int n  = nt * 16 + (l & 15);
  int k0 = t * 32 + (l >> 4) * 8 + j4 * 4;
  float v[4];
#pragma unroll
  for (int j = 0; j < 4; ++j) {
    int k = k0 + j;
    v[j] = (k < L) ? W[k * 512 + n] : 0.f;   // zero-pad k >= L
  }
  unsigned lo = (unsigned)f2b(v[0]) | ((unsigned)f2b(v[1]) << 16);
  unsigned hi = (unsigned)f2b(v[2]) | ((unsigned)f2b(v[3]) << 16);
  ((uint2*)wt)[i] = make_uint2(lo, hi);
}

// ---------------- fused GEMM + bias + ReLU + LayerNorm ---------------------------
// one workgroup = 64 rows x 512 cols (full N -> LN workgroup-local), 1024 threads.
// wave w owns ALL 64 rows x 32 cols (nt_g = 2w, 2w+1): acc = 4mt x 2nt x frag4
// = 32 VGPRs, leaving room for a 1-deep B prefetch (fixes round-1's VGPR=80
// serialization). B frags load coalesced (1KB/wave) from fragment-order wt
// (L2-resident). A slab staged ONCE to LDS (bf16, XOR-swizzled), no barriers
// in the K loop.
template <int S>
__device__ __forceinline__ void run_split(
    int blk, char* smem,
    const float* __restrict__ x, const unsigned short* __restrict__ wt,
    const float* __restrict__ bias, const float* __restrict__ gam,
    const float* __restrict__ bet, float* __restrict__ out) {
  constexpr int L     = (S == 0) ? 400 : 256;       // true K
  constexpr int KP    = (S == 0) ? 416 : 256;       // padded K (mult of 32)
  constexpr int NSTEP = KP / 32;
  constexpr int START = (S == 0) ? 0 : (S == 1) ? 400 : 15760;
  constexpr int KK    = (S == 0) ? 1 : (S == 1) ? 60 : 36;   // slices per batch row
  constexpr int OFF   = (S == 0) ? 0 : (S == 1) ? 1 : 61;    // row offset in output
  constexpr int WTO   = (S == 0) ? 0 : (S == 1) ? 212992 : 344064;
  constexpr int RS    = KP * 2;                     // LDS A row stride (bytes)
  // XOR swizzle needs row granule count (KP/8) to be a multiple of 8:
  // split1/2: 32 ok; split0: 52 -> skip (832B stride ~8-way conflict, 2% of work)
  constexpr bool SWZ  = (S != 0);

  unsigned short* A = (unsigned short*)smem;                 // [64][KP] (swizzled)
  float* red  = (float*)(smem + 64 * RS);                    // [16][64][2]
  float* stat = (float*)(smem + 64 * RS + 8192);             // [64][2]

  const int tid  = threadIdx.x;
  const int lane = tid & 63, w = tid >> 6;
  const int q = lane >> 4, c = lane & 15;
  const int m_base = blk * 64;

  // ---- B fragment pointers (fragment-order layout; lane*16B -> coalesced 1KB)
  const unsigned short* bp0 = wt + WTO + (2 * w) * (NSTEP * 512) + lane * 8;
  const unsigned short* bp1 = bp0 + NSTEP * 512;

  // prologue: B frags for t=0 in flight during A staging
  frag8 bc0 = *(const frag8*)bp0;
  frag8 bc1 = *(const frag8*)bp1;

  // ---- A staging: 64 rows, coalesced fp32 read -> bf16 -> swizzled LDS
  {
    int r = tid >> 4, ch = tid & 15;       // row, f4-chunk lane
    int m = m_base + r;
    int bb = m / KK, jj = m - bb * KK;     // const divisor -> magic mul
    const float* rp = x + (size_t)bb * TOTAL_DIM + START + (size_t)jj * L;
    constexpr int NPASS = (S == 0) ? 7 : 4;   // ceil((KP/4)/16)
#pragma unroll
    for (int p = 0; p < NPASS; ++p) {
      int c4 = ch + p * 16;
      if (S == 0 && c4 >= 104) continue;
      float4 v;
      if (S == 0 && c4 >= 100) {           // k 400..415 zero pad (400%4==0)
        v.x = 0.f; v.y = 0.f; v.z = 0.f; v.w = 0.f;
      } else {
        v = *(const float4*)(rp + c4 * 4);
      }
      unsigned lo = cvt2bf(v.x, v.y), hi = cvt2bf(v.z, v.w);
      int off = c4 * 8;
      if (SWZ) off ^= ((r & 7) << 4);
      *(uint2*)((char*)A + r * RS + off) = make_uint2(lo, hi);
    }
  }

  frag4 acc[4][2];
#pragma unroll
  for (int mt = 0; mt < 4; ++mt)
#pragma unroll
    for (int nt = 0; nt < 2; ++nt) {
      frag4 z = {0.f, 0.f, 0.f, 0.f};
      acc[mt][nt] = z;
    }

  __syncthreads();   // A slab ready (only barrier before epilogue)

  // row = mt*16 + c  ->  (row&7) == (c&7): swizzle term is mt-independent
  const int sw = SWZ ? ((c & 7) << 4) : 0;

  // ---- K loop: no barriers; 1-deep B prefetch; A frags from LDS (2-way, free)
#pragma unroll
  for (int t = 0; t < NSTEP; ++t) {
    frag8 bn0, bn1;
    const bool pre = (t + 1 < NSTEP);
    if (pre) {
      bn0 = *(const frag8*)(bp0 + (t + 1) * 512);
      bn1 = *(const frag8*)(bp1 + (t + 1) * 512);
    }
    frag8 af[4];
    const int off = (t * 64 + q * 16) ^ sw;
#pragma unroll
    for (int mt = 0; mt < 4; ++mt)
      af[mt] = *(const frag8*)((char*)A + (mt * 16 + c) * RS + off);
#pragma unroll
    for (int mt = 0; mt < 4; ++mt) {
      acc[mt][0] = __builtin_amdgcn_mfma_f32_16x16x32_bf16(af[mt], bc0, acc[mt][0], 0, 0, 0);
      acc[mt][1] = __builtin_amdgcn_mfma_f32_16x16x32_bf16(af[mt], bc1, acc[mt][1], 0, 0, 0);
    }
    if (pre) { bc0 = bn0; bc1 = bn1; }
  }

  // ---- epilogue: bias + ReLU + LayerNorm, all from registers
  const int colbase = w * 32 + c;
  float bv[2], gv[2], ev[2];
#pragma unroll
  for (int nt = 0; nt < 2; ++nt) {
    int col = colbase + nt * 16;
    bv[nt] = bias[col];
    gv[nt] = gam[col];
    ev[nt] = bet[col];
  }

  // C/D layout: col = lane&15 (c), row = q*4 + reg  [m89-verified]
#pragma unroll
  for (int mt = 0; mt < 4; ++mt) {
    float s[4] = {0.f, 0.f, 0.f, 0.f}, s2[4] = {0.f, 0.f, 0.f, 0.f};
#pragma unroll
    for (int nt = 0; nt < 2; ++nt)
#pragma unroll
      for (int r = 0; r < 4; ++r) {
        float h = acc[mt][nt][r] + bv[nt];
        h = fmaxf(h, 0.f);
        acc[mt][nt][r] = h;
        s[r] += h;
        s2[r] += h * h;
      }
#pragma unroll
    for (int r = 0; r < 4; ++r) {
      float a = s[r], b2 = s2[r];
#pragma unroll
      for (int msk = 1; msk < 16; msk <<= 1) {  // reduce 16 cols (same q group)
        a += __shfl_xor(a, msk, 64);
        b2 += __shfl_xor(b2, msk, 64);
      }
      if (c == 0) {
        int row = mt * 16 + q * 4 + r;
        red[(w * 64 + row) * 2 + 0] = a;
        red[(w * 64 + row) * 2 + 1] = b2;
      }
    }
  }
  __syncthreads();
  if (tid < 64) {
    float s = 0.f, s2 = 0.f;
#pragma unroll
    for (int ww = 0; ww < 16; ++ww) {
      s  += red[(ww * 64 + tid) * 2 + 0];
      s2 += red[(ww * 64 + tid) * 2 + 1];
    }
    float mu  = s * (1.f / 512.f);
    float var = s2 * (1.f / 512.f) - mu * mu;
    stat[tid * 2 + 0] = mu;
    stat[tid * 2 + 1] = rsqrtf(var + EPSLN);
  }
  __syncthreads();

#pragma unroll
  for (int mt = 0; mt < 4; ++mt)
#pragma unroll
    for (int r = 0; r < 4; ++r) {
      int row = mt * 16 + q * 4 + r;
      float mu = stat[row * 2 + 0], sc = stat[row * 2 + 1];
      int m = m_base + row;
      int bb = m / KK, jj = m - bb * KK;   // const divisor -> magic mul
      size_t orow = (size_t)bb * N_ROWS + OFF + jj;
      float* op = out + orow * D_MODEL + colbase;
#pragma unroll
      for (int nt = 0; nt < 2; ++nt)
        op[nt * 16] = (acc[mt][nt][r] - mu) * sc * gv[nt] + ev[nt];
    }
}

__global__ void __launch_bounds__(1024, 4) fused_kernel(
    const float* __restrict__ x, const unsigned short* __restrict__ wt,
    const float* __restrict__ b0, const float* __restrict__ g0, const float* __restrict__ e0,
    const float* __restrict__ b1, const float* __restrict__ g1, const float* __restrict__ e1,
    const float* __restrict__ b2, const float* __restrict__ g2, const float* __restrict__ e2,
    float* __restrict__ out) {
  extern __shared__ char smem[];
  int bid = blockIdx.x;
  if (bid < NB0)
    run_split<0>(bid, smem, x, wt, b0, g0, e0, out);
  else if (bid < NB0 + NB1)
    run_split<1>(bid - NB0, smem, x, wt, b1, g1, e1, out);
  else
    run_split<2>(bid - NB0 - NB1, smem, x, wt, b2, g2, e2, out);
}

// ---------------- fallback: fp32 vector path, zero workspace ---------------------
// one block = one output row. Correct-but-slow; only used if ws_size is too small.
template <int S>
__global__ void __launch_bounds__(256) fallback_split(
    const float* __restrict__ x, const float* __restrict__ W,
    const float* __restrict__ bias, const float* __restrict__ gam,
    const float* __restrict__ bet, float* __restrict__ out) {
  constexpr int L     = (S == 0) ? 400 : 256;
  constexpr int START = (S == 0) ? 0 : (S == 1) ? 400 : 15760;
  constexpr int KK    = (S == 0) ? 1 : (S == 1) ? 60 : 36;
  constexpr int OFF   = (S == 0) ? 0 : (S == 1) ? 1 : 61;

  __shared__ float xs[400];
  __shared__ float rs[4], rs2[4];

  int m = blockIdx.x;
  int bb = m / KK, jj = m - bb * KK;
  const float* xp = x + (size_t)bb * TOTAL_DIM + START + jj * L;
  for (int k = threadIdx.x; k < L; k += 256) xs[k] = xp[k];
  __syncthreads();

  float h[2];
#pragma unroll
  for (int i = 0; i < 2; ++i) {
    int col = threadIdx.x + i * 256;
    float acc = 0.f;
    for (int k = 0; k < L; ++k) acc += xs[k] * W[k * 512 + col];
    h[i] = fmaxf(acc + bias[col], 0.f);
  }

  float s = h[0] + h[1], s2 = h[0] * h[0] + h[1] * h[1];
#pragma unroll
  for (int msk = 1; msk < 64; msk <<= 1) {
    s  += __shfl_xor(s, msk, 64);
    s2 += __shfl_xor(s2, msk, 64);
  }
  int wave = threadIdx.x >> 6, lane = threadIdx.x & 63;
  if (lane == 0) { rs[wave] = s; rs2[wave] = s2; }
  __syncthreads();
  s  = rs[0] + rs[1] + rs[2] + rs[3];
  s2 = rs2[0] + rs2[1] + rs2[2] + rs2[3];
  float mu  = s * (1.f / 512.f);
  float var = s2 * (1.f / 512.f) - mu * mu;
  float sc  = rsqrtf(var + EPSLN);

  float* op = out + ((size_t)bb * N_ROWS + OFF + jj) * D_MODEL;
#pragma unroll
  for (int i = 0; i < 2; ++i) {
    int col = threadIdx.x + i * 256;
    op[col] = (h[i] - mu) * sc * gam[col] + bet[col];
  }
}

extern "C" void kernel_launch(void* const* d_in, const int* in_sizes, int n_in,
                              void* d_out, int out_size, void* d_ws, size_t ws_size,
                              hipStream_t stream) {
  const float* x  = (const float*)d_in[0];
  const float* W0 = (const float*)d_in[1];
  const float* b0 = (const float*)d_in[2];
  const float* g0 = (const float*)d_in[3];
  const float* e0 = (const float*)d_in[4];
  const float* W1 = (const float*)d_in[5];
  const float* b1 = (const float*)d_in[6];
  const float* g1 = (const float*)d_in[7];
  const float* e1 = (const float*)d_in[8];
  const float* W2 = (const float*)d_in[9];
  const float* b2 = (const float*)d_in[10];
  const float* g2 = (const float*)d_in[11];
  const float* e2 = (const float*)d_in[12];
  float* out = (float*)d_out;

  if (ws_size >= (size_t)WT_BYTES) {
    // fast path: bf16 MFMA, fused GEMM+bias+ReLU+LN
    unsigned short* wt = (unsigned short*)d_ws;
    prep_wt<<<464, 256, 0, stream>>>(W0, W1, W2, wt);
    fused_kernel<<<NB0 + NB1 + NB2, 1024, SMEM_FUSED, stream>>>(
        x, wt, b0, g0, e0, b1, g1, e1, b2, g2, e2, out);
  } else {
    // zero-workspace fp32 fallback (correct, slower)
    fallback_split<0><<<2048,   256, 0, stream>>>(x, W0, b0, g0, e0, out);
    fallback_split<1><<<122880, 256, 0, stream>>>(x, W1, b1, g1, e1, out);
    fallback_split<2><<<73728,  256, 0, stream>>>(x, W2, b2, g2, e2, out);
  }
}